// Round 4
// baseline (482.865 us; speedup 1.0000x reference)
//
#include <hip/hip_runtime.h>
#include <cmath>

#define D 128
#define BM 128   // block tile (rows and cols)
#define BK 64    // k-chunk staged in LDS
#define LOG2E 1.4426950408889634

typedef __attribute__((ext_vector_type(8))) _Float16 f16x8;
typedef __attribute__((ext_vector_type(4))) float f32x4;

// async global->LDS 16B copy (global_load_lds_dwordx4); LDS dst is
// lane-contiguous (wave-uniform base + lane*16) -- swizzle lives in gsrc.
__device__ __forceinline__ void async_cp16(const void* g, void* l) {
    __builtin_amdgcn_global_load_lds(
        (__attribute__((address_space(1))) void*)g,
        (__attribute__((address_space(3))) void*)l, 16, 0, 0);
}

// ---------------------------------------------------------------------------
// Prep: fp32 x -> fp16 (RTN) combined [x1; x2], per-row El[r] =
// -gamma*log2e*|row|^2 (log2-domain), AND zero the 64 acc slots + counter
// (block 0) -- replaces the separate hipMemsetAsync.
// ---------------------------------------------------------------------------
__global__ __launch_bounds__(256) void prep_kernel(
    const float* __restrict__ x1, const float* __restrict__ x2,
    _Float16* __restrict__ xh, float* __restrict__ El,
    double* __restrict__ acc, unsigned* __restrict__ cnt,
    float gl, int N) {
    int tid = threadIdx.x;
    if (blockIdx.x == 0) {
        if (tid < 64) acc[tid] = 0.0;
        else if (tid == 64) *cnt = 0u;
    }
    int r = blockIdx.x * 16 + (tid >> 4);
    if (r >= 2 * N) return;
    int l = tid & 15;
    const float* row = (r < N) ? x1 + (size_t)r * D : x2 + (size_t)(r - N) * D;
    float4 v0 = ((const float4*)row)[l * 2];
    float4 v1 = ((const float4*)row)[l * 2 + 1];
    float v[8] = {v0.x, v0.y, v0.z, v0.w, v1.x, v1.y, v1.z, v1.w};
    float p = 0.f;
    _Float16 h8[8];
#pragma unroll
    for (int j = 0; j < 8; ++j) {
        p = fmaf(v[j], v[j], p);
        h8[j] = (_Float16)v[j];   // RTN-even
    }
    *(uint4*)(xh + (size_t)r * D + l * 8) = *(uint4*)h8;
#pragma unroll
    for (int off = 8; off; off >>= 1) p += __shfl_down(p, off, 16);
    if (l == 0) El[r] = gl * p;   // gl = -gamma*log2e
}

// ---------------------------------------------------------------------------
// Main: one triangular pass over the combined (2N)x(2N) Gram matrix,
// fused finalize (completion-counter last-block pattern).
// Signed weight folds m11 - 2*m12 + m22 into ONE accumulator:
//   bi==bj: +1; same class off-diag: +2; cross class: -2.
// 128x128 tile, K in 2 chunks of 64. LDS exactly 32 KiB (A|B), float4-index
// XOR-swizzled by (row&7) -> 0 bank conflicts (R2/R3-measured).
// Entry = exp2(c2l*dot + El[i] + El[j]), raw v_exp_f32.
// launch_bounds(256,5): 5 blocks/CU (LDS 160/32 = 5), VGPR<=102.
// ---------------------------------------------------------------------------
__global__ __launch_bounds__(256, 5) void mmd_mfma_kernel(
    const _Float16* __restrict__ xh, const float* __restrict__ El,
    double* __restrict__ acc, unsigned* __restrict__ cnt,
    float* __restrict__ out, float c2l, int N, int nblocks) {
    __shared__ float4 smem[2048];  // 32 KiB exactly: [0,1024) A, [1024,2048) B

    // triangular decode (wave-uniform scalar math)
    int t = blockIdx.x;
    int bi = (int)((sqrtf(8.0f * t + 1.0f) - 1.0f) * 0.5f);
    while ((bi + 1) * (bi + 2) / 2 <= t) ++bi;
    while (bi * (bi + 1) / 2 > t) --bi;
    int bj = t - bi * (bi + 1) / 2;   // bj <= bi

    int half = N / BM;                 // first `half` block-rows are x1
    float w = (bi == bj) ? 1.0f : 2.0f;
    if ((bi < half) != (bj < half)) w = -2.0f;
    int aBase = bi * BM, bBase = bj * BM;

    int tid = threadIdx.x;
    int lane = tid & 63, wave = tid >> 6;
    int quad = lane >> 4, l16 = lane & 15;
    int wrow = (wave & 1) * 64, wcol = (wave >> 1) * 64;

    // hoisted LDS fragment offsets (float4 index), invariant across chunks
    int aoff[2][4], boff[2][4];
#pragma unroll
    for (int s = 0; s < 2; ++s) {
        int kc4 = s * 4 + quad;
#pragma unroll
        for (int u = 0; u < 4; ++u) {
            int ar = wrow + u * 16 + l16;
            aoff[s][u] = ar * 8 + (kc4 ^ (ar & 7));
            int br = wcol + u * 16 + l16;
            boff[s][u] = 1024 + br * 8 + (kc4 ^ (br & 7));
        }
    }

    f32x4 C[4][4];
#pragma unroll
    for (int i = 0; i < 4; ++i)
#pragma unroll
        for (int j = 0; j < 4; ++j) C[i][j] = {0.f, 0.f, 0.f, 0.f};

    for (int c = 0; c < 2; ++c) {
        if (c) __syncthreads();  // chunk-0 LDS reads done before overwrite
#pragma unroll
        for (int r = 0; r < 2; ++r) {
            int rowBase = r ? bBase : aBase;
#pragma unroll
            for (int i = 0; i < 4; ++i) {
                int slot = i * 256 + tid;            // 0..1023
                int row = slot >> 3, g = slot & 7;
                int kc4 = g ^ (row & 7);
                const void* gp = xh + ((size_t)(rowBase + row) * D + c * BK + kc4 * 8);
                async_cp16(gp, &smem[r * 1024 + slot]);
            }
        }
        __syncthreads();
#pragma unroll
        for (int s = 0; s < 2; ++s) {
            f16x8 a[4], b[4];
#pragma unroll
            for (int u = 0; u < 4; ++u) {
                a[u] = *(const f16x8*)&smem[aoff[s][u]];
                b[u] = *(const f16x8*)&smem[boff[s][u]];
            }
#pragma unroll
            for (int ti = 0; ti < 4; ++ti)
#pragma unroll
                for (int tj = 0; tj < 4; ++tj)
                    C[ti][tj] = __builtin_amdgcn_mfma_f32_16x16x32_f16(a[ti], b[tj], C[ti][tj], 0, 0, 0);
        }
    }

    // Epilogue. C/D layout (m89-verified): col = lane&15, row = quad*4 + reg.
    // entry = exp2(c2l*dot + El[row] + El[col]); sum in fp32 per-thread.
    float lsum = 0.f;
    int arow0 = aBase + wrow + quad * 4;
    int bcol0 = bBase + wcol + l16;
#pragma unroll
    for (int ti = 0; ti < 4; ++ti) {
        float4 ea = *(const float4*)&El[arow0 + ti * 16];
#pragma unroll
        for (int tj = 0; tj < 4; ++tj) {
            float eb = El[bcol0 + tj * 16];
            f32x4 d = C[ti][tj];
            lsum += __builtin_amdgcn_exp2f(fmaf(c2l, d.x, ea.x + eb))
                  + __builtin_amdgcn_exp2f(fmaf(c2l, d.y, ea.y + eb))
                  + __builtin_amdgcn_exp2f(fmaf(c2l, d.z, ea.z + eb))
                  + __builtin_amdgcn_exp2f(fmaf(c2l, d.w, ea.w + eb));
        }
    }
    double ds = (double)lsum * (double)w;
#pragma unroll
    for (int off = 32; off; off >>= 1) ds += __shfl_down(ds, off);
    __syncthreads();  // LDS frag reads all done; reuse tile buffer as scratch
    double* red = (double*)smem;
    volatile unsigned* flag = ((volatile unsigned*)smem) + 16;
    if (lane == 0) red[wave] = ds;
    __syncthreads();
    if (tid == 0) {
        atomicAdd(&acc[(bi + bj) & 63], red[0] + red[1] + red[2] + red[3]);
        __threadfence();
        unsigned old = atomicAdd(cnt, 1u);
        *flag = (old == (unsigned)(nblocks - 1)) ? 1u : 0u;
    }
    __syncthreads();
    if (*flag) {
        // last block: coherent re-read of all 64 slots via atomic RMW
        if (tid < 64) {
            double v = atomicAdd(&acc[tid], 0.0);
#pragma unroll
            for (int off = 32; off; off >>= 1) v += __shfl_down(v, off);
            if (tid == 0) {
                double nn = (double)N * (double)N;
                double s2 = v / nn;
                out[0] = (float)sqrt(s2 > 0.0 ? s2 : 0.0);
            }
        }
    }
}

extern "C" void kernel_launch(void* const* d_in, const int* in_sizes, int n_in,
                              void* d_out, int out_size, void* d_ws, size_t ws_size,
                              hipStream_t stream) {
    const float* x1 = (const float*)d_in[0];
    const float* x2 = (const float*)d_in[1];
    int N = in_sizes[0] / D;  // 8192

    // ws layout: [0,512) acc (64 doubles); cnt @512; El @8192 (2N f32);
    // xh @73728 (2N*128 fp16 = 4 MB). Total ~4.07 MB.
    double* acc = (double*)d_ws;
    unsigned* cnt = (unsigned*)((char*)d_ws + 512);
    float* El = (float*)((char*)d_ws + 8192);
    _Float16* xh = (_Float16*)((char*)d_ws + 73728);

    double lg = lgamma(0.5 * (D + 1)) - lgamma(0.5 * D);
    double gz = 2.0 * exp(lg);
    double gamma = 1.0 / (2.0 * gz * gz);
    float gl = (float)(-gamma * LOG2E);        // El scale
    float c2l = (float)(2.0 * gamma * LOG2E);  // dot scale (log2 domain)

    prep_kernel<<<(2 * N + 15) / 16, 256, 0, stream>>>(x1, x2, xh, El, acc, cnt, gl, N);

    int nt2 = 2 * N / BM;                  // 128 combined block-rows
    int nblocks = nt2 * (nt2 + 1) / 2;     // 8256 triangular blocks
    mmd_mfma_kernel<<<nblocks, 256, 0, stream>>>(xh, El, acc, cnt,
                                                 (float*)d_out, c2l, N, nblocks);
}

// Round 5
// 268.137 us; speedup vs baseline: 1.8008x; 1.8008x over previous
//
#include <hip/hip_runtime.h>
#include <cmath>

#define D 128
#define BM 128   // block tile (rows and cols)
#define BK 64    // k-chunk staged in LDS
#define LOG2E 1.4426950408889634

typedef __attribute__((ext_vector_type(8))) _Float16 f16x8;
typedef __attribute__((ext_vector_type(4))) float f32x4;

// async global->LDS 16B copy (global_load_lds_dwordx4); LDS dst is
// lane-contiguous (wave-uniform base + lane*16) -- swizzle lives in gsrc.
__device__ __forceinline__ void async_cp16(const void* g, void* l) {
    __builtin_amdgcn_global_load_lds(
        (__attribute__((address_space(1))) void*)g,
        (__attribute__((address_space(3))) void*)l, 16, 0, 0);
}

// ---------------------------------------------------------------------------
// Prep: fp32 x -> fp16 (RTN) combined [x1; x2], per-row El[r] =
// -gamma*log2e*|row|^2 (log2-domain), AND zero the 64 acc slots + counter
// (block 0) -- replaces a separate hipMemsetAsync dispatch.
// ---------------------------------------------------------------------------
__global__ __launch_bounds__(256) void prep_kernel(
    const float* __restrict__ x1, const float* __restrict__ x2,
    _Float16* __restrict__ xh, float* __restrict__ El,
    double* __restrict__ acc, unsigned* __restrict__ cnt,
    float gl, int N) {
    int tid = threadIdx.x;
    if (blockIdx.x == 0) {
        if (tid < 64) acc[tid] = 0.0;
        else if (tid == 64) *cnt = 0u;
    }
    int r = blockIdx.x * 16 + (tid >> 4);
    if (r >= 2 * N) return;
    int l = tid & 15;
    const float* row = (r < N) ? x1 + (size_t)r * D : x2 + (size_t)(r - N) * D;
    float4 v0 = ((const float4*)row)[l * 2];
    float4 v1 = ((const float4*)row)[l * 2 + 1];
    float v[8] = {v0.x, v0.y, v0.z, v0.w, v1.x, v1.y, v1.z, v1.w};
    float p = 0.f;
    _Float16 h8[8];
#pragma unroll
    for (int j = 0; j < 8; ++j) {
        p = fmaf(v[j], v[j], p);
        h8[j] = (_Float16)v[j];   // RTN-even
    }
    *(uint4*)(xh + (size_t)r * D + l * 8) = *(uint4*)h8;
#pragma unroll
    for (int off = 8; off; off >>= 1) p += __shfl_down(p, off, 16);
    if (l == 0) El[r] = gl * p;   // gl = -gamma*log2e
}

// ---------------------------------------------------------------------------
// Main: one triangular pass over the combined (2N)x(2N) Gram matrix,
// fused finalize (completion-counter last-block pattern).
// Signed weight folds m11 - 2*m12 + m22 into ONE accumulator:
//   bi==bj: +1; same class off-diag: +2; cross class: -2.
// 128x128 tile, K in 2 chunks of 64. LDS exactly 32 KiB (A|B), float4-index
// XOR-swizzled by (row&7) -> 0 bank conflicts (R2/R3-measured).
// Entry = exp2(c2l*dot + El[i] + El[j]), raw v_exp_f32.
//
// REGISTER BUDGET (R4 post-mortem): C[4][4] = 64 AGPR + ~60 VGPR = 124.
// launch_bounds(256,4) -> 128 regs/wave: fits (R3 measured 60 VGPR, no
// spill). (256,5) -> 96 regs/wave: compiler SPILLED the accumulators ->
// 540 MB scratch HBM traffic, 430 us (R4). Do not raise the bound.
// ---------------------------------------------------------------------------
__global__ __launch_bounds__(256, 4) void mmd_mfma_kernel(
    const _Float16* __restrict__ xh, const float* __restrict__ El,
    double* __restrict__ acc, unsigned* __restrict__ cnt,
    float* __restrict__ out, float c2l, int N, int nblocks) {
    __shared__ float4 smem[2048];  // 32 KiB exactly: [0,1024) A, [1024,2048) B

    // triangular decode (wave-uniform scalar math)
    int t = blockIdx.x;
    int bi = (int)((sqrtf(8.0f * t + 1.0f) - 1.0f) * 0.5f);
    while ((bi + 1) * (bi + 2) / 2 <= t) ++bi;
    while (bi * (bi + 1) / 2 > t) --bi;
    int bj = t - bi * (bi + 1) / 2;   // bj <= bi

    int half = N / BM;                 // first `half` block-rows are x1
    float w = (bi == bj) ? 1.0f : 2.0f;
    if ((bi < half) != (bj < half)) w = -2.0f;
    int aBase = bi * BM, bBase = bj * BM;

    int tid = threadIdx.x;
    int lane = tid & 63, wave = tid >> 6;
    int quad = lane >> 4, l16 = lane & 15;
    int wrow = (wave & 1) * 64, wcol = (wave >> 1) * 64;

    f32x4 C[4][4];
#pragma unroll
    for (int i = 0; i < 4; ++i)
#pragma unroll
        for (int j = 0; j < 4; ++j) C[i][j] = {0.f, 0.f, 0.f, 0.f};

    for (int c = 0; c < 2; ++c) {
        if (c) __syncthreads();  // chunk-0 LDS reads done before overwrite
#pragma unroll
        for (int r = 0; r < 2; ++r) {
            int rowBase = r ? bBase : aBase;
#pragma unroll
            for (int i = 0; i < 4; ++i) {
                int slot = i * 256 + tid;            // 0..1023
                int row = slot >> 3, g = slot & 7;
                int kc4 = g ^ (row & 7);
                const void* gp = xh + ((size_t)(rowBase + row) * D + c * BK + kc4 * 8);
                async_cp16(gp, &smem[r * 1024 + slot]);
            }
        }
        __syncthreads();
#pragma unroll
        for (int s = 0; s < 2; ++s) {
            int kc4 = s * 4 + quad;
            f16x8 a[4], b[4];
#pragma unroll
            for (int u = 0; u < 4; ++u) {
                int ar = wrow + u * 16 + l16;
                a[u] = *(const f16x8*)&smem[ar * 8 + (kc4 ^ (ar & 7))];
                int br = wcol + u * 16 + l16;
                b[u] = *(const f16x8*)&smem[1024 + br * 8 + (kc4 ^ (br & 7))];
            }
#pragma unroll
            for (int ti = 0; ti < 4; ++ti)
#pragma unroll
                for (int tj = 0; tj < 4; ++tj)
                    C[ti][tj] = __builtin_amdgcn_mfma_f32_16x16x32_f16(a[ti], b[tj], C[ti][tj], 0, 0, 0);
        }
    }

    // Epilogue. C/D layout (m89-verified): col = lane&15, row = quad*4 + reg.
    // entry = exp2(c2l*dot + El[row] + El[col]); fp32 per-thread sum.
    float lsum = 0.f;
    int arow0 = aBase + wrow + quad * 4;
    int bcol0 = bBase + wcol + l16;
#pragma unroll
    for (int ti = 0; ti < 4; ++ti) {
        float4 ea = *(const float4*)&El[arow0 + ti * 16];
#pragma unroll
        for (int tj = 0; tj < 4; ++tj) {
            float eb = El[bcol0 + tj * 16];
            f32x4 d = C[ti][tj];
            lsum += __builtin_amdgcn_exp2f(fmaf(c2l, d.x, ea.x + eb))
                  + __builtin_amdgcn_exp2f(fmaf(c2l, d.y, ea.y + eb))
                  + __builtin_amdgcn_exp2f(fmaf(c2l, d.z, ea.z + eb))
                  + __builtin_amdgcn_exp2f(fmaf(c2l, d.w, ea.w + eb));
        }
    }
    double ds = (double)lsum * (double)w;
#pragma unroll
    for (int off = 32; off; off >>= 1) ds += __shfl_down(ds, off);
    __syncthreads();  // LDS frag reads all done; reuse tile buffer as scratch
    double* red = (double*)smem;
    volatile unsigned* flag = ((volatile unsigned*)smem) + 16;
    if (lane == 0) red[wave] = ds;
    __syncthreads();
    if (tid == 0) {
        atomicAdd(&acc[(bi + bj) & 63], red[0] + red[1] + red[2] + red[3]);
        __threadfence();
        unsigned old = atomicAdd(cnt, 1u);
        *flag = (old == (unsigned)(nblocks - 1)) ? 1u : 0u;
    }
    __syncthreads();
    if (*flag) {
        // last block: coherent re-read of all 64 slots via atomic RMW
        if (tid < 64) {
            double v = atomicAdd(&acc[tid], 0.0);
#pragma unroll
            for (int off = 32; off; off >>= 1) v += __shfl_down(v, off);
            if (tid == 0) {
                double nn = (double)N * (double)N;
                double s2 = v / nn;
                out[0] = (float)sqrt(s2 > 0.0 ? s2 : 0.0);
            }
        }
    }
}

extern "C" void kernel_launch(void* const* d_in, const int* in_sizes, int n_in,
                              void* d_out, int out_size, void* d_ws, size_t ws_size,
                              hipStream_t stream) {
    const float* x1 = (const float*)d_in[0];
    const float* x2 = (const float*)d_in[1];
    int N = in_sizes[0] / D;  // 8192

    // ws layout: [0,512) acc (64 doubles); cnt @512; El @8192 (2N f32);
    // xh @73728 (2N*128 fp16 = 4 MB). Total ~4.07 MB.
    double* acc = (double*)d_ws;
    unsigned* cnt = (unsigned*)((char*)d_ws + 512);
    float* El = (float*)((char*)d_ws + 8192);
    _Float16* xh = (_Float16*)((char*)d_ws + 73728);

    double lg = lgamma(0.5 * (D + 1)) - lgamma(0.5 * D);
    double gz = 2.0 * exp(lg);
    double gamma = 1.0 / (2.0 * gz * gz);
    float gl = (float)(-gamma * LOG2E);        // El scale
    float c2l = (float)(2.0 * gamma * LOG2E);  // dot scale (log2 domain)

    prep_kernel<<<(2 * N + 15) / 16, 256, 0, stream>>>(x1, x2, xh, El, acc, cnt, gl, N);

    int nt2 = 2 * N / BM;                  // 128 combined block-rows
    int nblocks = nt2 * (nt2 + 1) / 2;     // 8256 triangular blocks
    mmd_mfma_kernel<<<nblocks, 256, 0, stream>>>(xh, El, acc, cnt,
                                                 (float*)d_out, c2l, N, nblocks);
}

// Round 7
// 110.709 us; speedup vs baseline: 4.3616x; 2.4220x over previous
//
#include <hip/hip_runtime.h>
#include <cmath>

#define D 128
#define BM 128   // block tile (rows and cols)
#define BK 64    // k-chunk staged in LDS
#define LOG2E 1.4426950408889634

typedef __attribute__((ext_vector_type(8))) _Float16 f16x8;
typedef __attribute__((ext_vector_type(4))) float f32x4;
typedef __attribute__((ext_vector_type(2))) float f32x2;

// async global->LDS 16B copy (global_load_lds_dwordx4); LDS dst is
// lane-contiguous (wave-uniform base + lane*16) -- swizzle lives in gsrc.
__device__ __forceinline__ void async_cp16(const void* g, void* l) {
    __builtin_amdgcn_global_load_lds(
        (__attribute__((address_space(1))) void*)g,
        (__attribute__((address_space(3))) void*)l, 16, 0, 0);
}

// ---------------------------------------------------------------------------
// Prep: fp32 x -> fp16 (RTN) combined [x1; x2], per-row El[r] =
// -gamma*log2e*|row|^2 (log2-domain), AND zero the 64 acc slots (block 0).
// ---------------------------------------------------------------------------
__global__ __launch_bounds__(256) void prep_kernel(
    const float* __restrict__ x1, const float* __restrict__ x2,
    _Float16* __restrict__ xh, float* __restrict__ El,
    double* __restrict__ acc, float gl, int N) {
    int tid = threadIdx.x;
    if (blockIdx.x == 0 && tid < 64) acc[tid] = 0.0;
    int r = blockIdx.x * 16 + (tid >> 4);
    if (r >= 2 * N) return;
    int l = tid & 15;
    const float* row = (r < N) ? x1 + (size_t)r * D : x2 + (size_t)(r - N) * D;
    float4 v0 = ((const float4*)row)[l * 2];
    float4 v1 = ((const float4*)row)[l * 2 + 1];
    float v[8] = {v0.x, v0.y, v0.z, v0.w, v1.x, v1.y, v1.z, v1.w};
    float p = 0.f;
    _Float16 h8[8];
#pragma unroll
    for (int j = 0; j < 8; ++j) {
        p = fmaf(v[j], v[j], p);
        h8[j] = (_Float16)v[j];   // RTN-even
    }
    *(uint4*)(xh + (size_t)r * D + l * 8) = *(uint4*)h8;
#pragma unroll
    for (int off = 8; off; off >>= 1) p += __shfl_down(p, off, 16);
    if (l == 0) El[r] = gl * p;   // gl = -gamma*log2e
}

// ---------------------------------------------------------------------------
// Main: one triangular pass over the combined (2N)x(2N) Gram matrix.
// Signed weight folds m11 - 2*m12 + m22 into ONE accumulator:
//   bi==bj: +1; same class off-diag: +2; cross class: -2.
// 128x128 tile, K in 2 chunks of 64. LDS exactly 32 KiB (A|B), float4-index
// XOR-swizzled by (row&7) -> 0 bank conflicts (measured R2-R5).
// Entry = exp2(c2l*dot + El[i]) * 2^El[j] (log2 domain, eb factored/column).
// Epilogue in PLAIN vector C (f32x2 operators): the compiler lowers to
// v_pk_fma_f32 etc. with correct register classes.
//   R6 post-mortem: hand inline-asm v_pk_fma_f32 silently computed garbage
//   (sum went negative -> clamped 0 output). Never hand-asm VOP3P.
//
// REGISTER BUDGET (R4 post-mortem): C[4][4]=64 AGPR + ~60 VGPR fits the
// 128-reg budget of launch_bounds(256,4). (256,5) -> 96 regs: SPILLS the
// accumulators -> 540 MB scratch traffic, 430 us. Do not raise.
//
// NO __threadfence here (R5 post-mortem): per-block agent fence =
// buffer_wbl2+inv per block = continuous L2 flush -> 54 -> 212 us.
// Finalize stays a separate kernel; the kernel boundary is the release.
// ---------------------------------------------------------------------------
__global__ __launch_bounds__(256, 4) void mmd_mfma_kernel(
    const _Float16* __restrict__ xh, const float* __restrict__ El,
    double* __restrict__ acc, float c2l, int N) {
    __shared__ float4 smem[2048];  // 32 KiB exactly: [0,1024) A, [1024,2048) B

    // triangular decode (wave-uniform scalar math)
    int t = blockIdx.x;
    int bi = (int)((sqrtf(8.0f * t + 1.0f) - 1.0f) * 0.5f);
    while ((bi + 1) * (bi + 2) / 2 <= t) ++bi;
    while (bi * (bi + 1) / 2 > t) --bi;
    int bj = t - bi * (bi + 1) / 2;   // bj <= bi

    int half = N / BM;                 // first `half` block-rows are x1
    float w = (bi == bj) ? 1.0f : 2.0f;
    if ((bi < half) != (bj < half)) w = -2.0f;
    int aBase = bi * BM, bBase = bj * BM;

    int tid = threadIdx.x;
    int lane = tid & 63, wave = tid >> 6;
    int quad = lane >> 4, l16 = lane & 15;
    int wrow = (wave & 1) * 64, wcol = (wave >> 1) * 64;

    f32x4 C[4][4];
#pragma unroll
    for (int i = 0; i < 4; ++i)
#pragma unroll
        for (int j = 0; j < 4; ++j) C[i][j] = {0.f, 0.f, 0.f, 0.f};

    for (int c = 0; c < 2; ++c) {
        if (c) __syncthreads();  // chunk-0 LDS reads done before overwrite
#pragma unroll
        for (int r = 0; r < 2; ++r) {
            int rowBase = r ? bBase : aBase;
#pragma unroll
            for (int i = 0; i < 4; ++i) {
                int slot = i * 256 + tid;            // 0..1023
                int row = slot >> 3, g = slot & 7;
                int kc4 = g ^ (row & 7);
                const void* gp = xh + ((size_t)(rowBase + row) * D + c * BK + kc4 * 8);
                async_cp16(gp, &smem[r * 1024 + slot]);
            }
        }
        __syncthreads();
#pragma unroll
        for (int s = 0; s < 2; ++s) {
            int kc4 = s * 4 + quad;
            f16x8 a[4], b[4];
#pragma unroll
            for (int u = 0; u < 4; ++u) {
                int ar = wrow + u * 16 + l16;
                a[u] = *(const f16x8*)&smem[ar * 8 + (kc4 ^ (ar & 7))];
                int br = wcol + u * 16 + l16;
                b[u] = *(const f16x8*)&smem[1024 + br * 8 + (kc4 ^ (br & 7))];
            }
#pragma unroll
            for (int ti = 0; ti < 4; ++ti)
#pragma unroll
                for (int tj = 0; tj < 4; ++tj)
                    C[ti][tj] = __builtin_amdgcn_mfma_f32_16x16x32_f16(a[ti], b[tj], C[ti][tj], 0, 0, 0);
        }
    }

    // Epilogue. C/D layout (m89-verified): col = lane&15, row = quad*4 + reg.
    // entry = exp2(c2l*d + ea) * 2^eb, eb factored per column; plain vector C.
    int arow0 = aBase + wrow + quad * 4;
    int bcol0 = bBase + wcol + l16;
    float4 ea4[4];
#pragma unroll
    for (int ti = 0; ti < 4; ++ti) ea4[ti] = *(const float4*)&El[arow0 + ti * 16];
    f32x2 cc = {c2l, c2l};
    float lsum = 0.f;
#pragma unroll
    for (int tj = 0; tj < 4; ++tj) {
        float eb = El[bcol0 + tj * 16];
        f32x2 p = {0.f, 0.f};
#pragma unroll
        for (int ti = 0; ti < 4; ++ti) {
            f32x4 d = C[ti][tj];
            f32x2 a01 = cc * f32x2{d.x, d.y} + f32x2{ea4[ti].x, ea4[ti].y};
            f32x2 a23 = cc * f32x2{d.z, d.w} + f32x2{ea4[ti].z, ea4[ti].w};
            f32x2 e;
            e.x = __builtin_amdgcn_exp2f(a01.x);
            e.y = __builtin_amdgcn_exp2f(a01.y);
            f32x2 e2;
            e2.x = __builtin_amdgcn_exp2f(a23.x);
            e2.y = __builtin_amdgcn_exp2f(a23.y);
            p += e + e2;
        }
        lsum = fmaf(p.x + p.y, __builtin_amdgcn_exp2f(eb), lsum);
    }
    double ds = (double)lsum * (double)w;
#pragma unroll
    for (int off = 32; off; off >>= 1) ds += __shfl_down(ds, off);
    __syncthreads();  // LDS frag reads all done; reuse tile buffer as scratch
    double* red = (double*)smem;
    if (lane == 0) red[wave] = ds;
    __syncthreads();
    if (tid == 0)
        atomicAdd(&acc[(bi + bj) & 63], red[0] + red[1] + red[2] + red[3]);
}

// ---------------------------------------------------------------------------
// Finalize: out = sqrt(max(S/N^2, 0)), S already = S11 + S22 - 2*S12.
// ---------------------------------------------------------------------------
__global__ __launch_bounds__(64) void mmd_finalize_kernel(
    const double* __restrict__ acc, float* __restrict__ out, int N) {
    int l = threadIdx.x;
    double v = acc[l];
#pragma unroll
    for (int off = 32; off; off >>= 1) v += __shfl_down(v, off);
    if (l == 0) {
        double nn = (double)N * (double)N;
        double s = v / nn;
        out[0] = (float)sqrt(s > 0.0 ? s : 0.0);
    }
}

extern "C" void kernel_launch(void* const* d_in, const int* in_sizes, int n_in,
                              void* d_out, int out_size, void* d_ws, size_t ws_size,
                              hipStream_t stream) {
    const float* x1 = (const float*)d_in[0];
    const float* x2 = (const float*)d_in[1];
    int N = in_sizes[0] / D;  // 8192

    // ws layout: [0,512) acc (64 doubles); El @8192 (2N f32);
    // xh @73728 (2N*128 fp16 = 4 MB). Total ~4.07 MB.
    double* acc = (double*)d_ws;
    float* El = (float*)((char*)d_ws + 8192);
    _Float16* xh = (_Float16*)((char*)d_ws + 73728);

    double lg = lgamma(0.5 * (D + 1)) - lgamma(0.5 * D);
    double gz = 2.0 * exp(lg);
    double gamma = 1.0 / (2.0 * gz * gz);
    float gl = (float)(-gamma * LOG2E);        // El scale
    float c2l = (float)(2.0 * gamma * LOG2E);  // dot scale (log2 domain)

    prep_kernel<<<(2 * N + 15) / 16, 256, 0, stream>>>(x1, x2, xh, El, acc, gl, N);

    int nt2 = 2 * N / BM;                  // 128 combined block-rows
    int nblocks = nt2 * (nt2 + 1) / 2;     // 8256 triangular blocks
    mmd_mfma_kernel<<<nblocks, 256, 0, stream>>>(xh, El, acc, c2l, N);

    mmd_finalize_kernel<<<1, 64, 0, stream>>>(acc, (float*)d_out, N);
}